// Round 20
// baseline (302.820 us; speedup 1.0000x reference)
//
#include <hip/hip_runtime.h>
#include <hip/hip_bf16.h>
#include <stdint.h>

// ---------------- constants ----------------
#define B_SZ   256
#define LSTM_N 512
#define FEAT_N 4632
#define FV_N   4608
#define CIN_N  6144
#define HALF_CIN 3072
#define ACT_N  64
#define LD_FEAT 4672   // 64-mult >= 4632
#define LD_ZEXT 576    // 64-mult >= 528

typedef __attribute__((ext_vector_type(8))) short bf16x8;
typedef __attribute__((ext_vector_type(4))) float f32x4;

__device__ __forceinline__ short f2bf(float f) {
  uint32_t u = __float_as_uint(f);
  u += 0x7FFFu + ((u >> 16) & 1u);
  return (short)(u >> 16);
}
__device__ __forceinline__ float bf2f(short s) {
  return __uint_as_float(((uint32_t)(uint16_t)s) << 16);
}
// truncation pack: two f32 -> two bf16 in one u32
__device__ __forceinline__ uint32_t pack2(float x, float y) {
  return (__float_as_uint(x) >> 16) | (__float_as_uint(y) & 0xffff0000u);
}

// async global->LDS DMA, 16B per lane; LDS dest = wave-uniform base + lane*16
typedef __attribute__((address_space(3))) void lds_void_t;
typedef const __attribute__((address_space(1))) void gbl_void_t;
__device__ __forceinline__ void lds_dma16(const void* g, void* l) {
  __builtin_amdgcn_global_load_lds((gbl_void_t*)g, (lds_void_t*)l, 16, 0, 0);
}

// ---------------- threefry2x32 (matches jax) ----------------
__device__ __forceinline__ uint32_t rotl32(uint32_t x, int r) {
  return (x << r) | (x >> (32 - r));
}
__device__ __forceinline__ void threefry2x32(uint32_t k0, uint32_t k1,
                                             uint32_t x0, uint32_t x1,
                                             uint32_t& o0, uint32_t& o1) {
  uint32_t k2 = k0 ^ k1 ^ 0x1BD11BDAu;
  x0 += k0; x1 += k1;
  x0 += x1; x1 = rotl32(x1, 13); x1 ^= x0;
  x0 += x1; x1 = rotl32(x1, 15); x1 ^= x0;
  x0 += x1; x1 = rotl32(x1, 26); x1 ^= x0;
  x0 += x1; x1 = rotl32(x1,  6); x1 ^= x0;
  x0 += k1; x1 += k2 + 1u;
  x0 += x1; x1 = rotl32(x1, 17); x1 ^= x0;
  x0 += x1; x1 = rotl32(x1, 29); x1 ^= x0;
  x0 += x1; x1 = rotl32(x1, 16); x1 ^= x0;
  x0 += x1; x1 = rotl32(x1, 24); x1 ^= x0;
  x0 += k2; x1 += k0 + 2u;
  x0 += x1; x1 = rotl32(x1, 13); x1 ^= x0;
  x0 += x1; x1 = rotl32(x1, 15); x1 ^= x0;
  x0 += x1; x1 = rotl32(x1, 26); x1 ^= x0;
  x0 += x1; x1 = rotl32(x1,  6); x1 ^= x0;
  x0 += k0; x1 += k1 + 3u;
  x0 += x1; x1 = rotl32(x1, 17); x1 ^= x0;
  x0 += x1; x1 = rotl32(x1, 29); x1 ^= x0;
  x0 += x1; x1 = rotl32(x1, 16); x1 ^= x0;
  x0 += x1; x1 = rotl32(x1, 24); x1 ^= x0;
  x0 += k1; x1 += k2 + 4u;
  x0 += x1; x1 = rotl32(x1, 13); x1 ^= x0;
  x0 += x1; x1 = rotl32(x1, 15); x1 ^= x0;
  x0 += x1; x1 = rotl32(x1, 26); x1 ^= x0;
  x0 += x1; x1 = rotl32(x1,  6); x1 ^= x0;
  x0 += k2; x1 += k0 + 5u;
  o0 = x0; o1 = x1;
}

// ---------------- concat canvases + cvt to bf16 ----------------
__global__ void concat_cvt_kernel(const float* __restrict__ act,
                                  const float* __restrict__ obj,
                                  short* __restrict__ xb) {
  int idx = blockIdx.x * 256 + threadIdx.x;
  if (idx >= B_SZ * 768) return;
  int row = idx / 768;
  int c8 = (idx - row * 768) * 8;
  const float* src = (c8 < HALF_CIN) ? (act + (size_t)row * HALF_CIN + c8)
                                     : (obj + (size_t)row * HALF_CIN + (c8 - HALF_CIN));
  float4 u = ((const float4*)src)[0];
  float4 v = ((const float4*)src)[1];
  bf16x8 r;
  r[0]=f2bf(u.x); r[1]=f2bf(u.y); r[2]=f2bf(u.z); r[3]=f2bf(u.w);
  r[4]=f2bf(v.x); r[5]=f2bf(v.y); r[6]=f2bf(v.z); r[7]=f2bf(v.w);
  *(bf16x8*)&xb[(size_t)row * CIN_N + c8] = r;
}

// ---------------- gumbel table: gum[4][256][64] ----------------
__global__ void gumbel_kernel(float* __restrict__ gum) {
  int idx = blockIdx.x * 256 + threadIdx.x;
  if (idx >= 4 * 16384) return;
  int k = idx >> 14;
  uint32_t j = (uint32_t)(idx & 16383);
  uint32_t f0, f1, o0, o1, bits;
  threefry2x32(0u, 42u, 0u, (uint32_t)k, f0, f1);
  if (j < 8192u) { threefry2x32(f0, f1, j, j + 8192u, o0, o1); bits = o0; }
  else           { threefry2x32(f0, f1, j - 8192u, j, o0, o1); bits = o1; }
  const float tiny = 1.17549435e-38f;
  float fu = __uint_as_float((bits >> 9) | 0x3f800000u) - 1.0f;
  float u = fmaxf(tiny, fu * (1.0f - tiny) + tiny);
  gum[idx] = -logf(-logf(u));
}

// ---------------- embeddings into feats + zero pad ----------------
__global__ void fill_embs_kernel(const int* __restrict__ lastpos,
                                 const int* __restrict__ ep,
                                 const float* __restrict__ emb_end,
                                 const float* __restrict__ emb_ep,
                                 short* __restrict__ feats) {
  int b = blockIdx.x;
  int t = threadIdx.x;   // 0..63
  short* row = feats + (size_t)b * LD_FEAT;
  if (t < 16)      row[FV_N + t] = f2bf(emb_end[lastpos[b] * 16 + t]);
  else if (t < 24) row[FV_N + 16 + (t - 16)] = f2bf(emb_ep[ep[b] * 8 + (t - 16)]);
  else             row[FV_N + t] = 0;
}

// ---------------- GEMM v11 (round-15 best): DMA W staging, 128m x 64n / block ----------
__global__ __launch_bounds__(512, 6) void gemm6_kernel(
    const short* __restrict__ A, int ldab,
    const float* __restrict__ W, int ldw,
    const float* __restrict__ Wend,           // W + N*ldw
    short* __restrict__ P, int nblk,
    int N, int Kiter, int kc, int nchunks) {
  __shared__ float Wlds[2][64 * 64];

  const int tid = threadIdx.x;
  const int w = tid >> 6, l = tid & 63, l15 = l & 15, lg = l >> 4;
  const int mb = blockIdx.x & 1;
  const int n0 = (blockIdx.x >> 1) * 64;
  const int Np = nblk * 64;
  const int ks = blockIdx.y;
  const int kbeg = ks * kc;
  const int kend = (kbeg + kc < Kiter) ? (kbeg + kc) : Kiter;
  const int nk = (kend - kbeg) >> 6;
  const int mrow = mb * 128 + (w << 4);      // 16 m-rows per wave

  const char* wlim = (const char*)Wend - 16;

  f32x4 acc[4];
#pragma unroll
  for (int j = 0; j < 4; ++j) acc[j] = (f32x4){0.f, 0.f, 0.f, 0.f};

  auto dma = [&](int kt, int buf) {
#pragma unroll
    for (int q = 0; q < 2; ++q) {
      int r = (w << 3) + (q << 2) + (l >> 4);   // tile row 0..63
      int gn = n0 + r; if (gn >= N) gn = N - 1;
      int g16 = (l & 15) ^ (r & 15);            // source granule (pre-swizzle)
      const char* src = (const char*)(W + (size_t)gn * ldw + kt) + g16 * 16;
      if (src > wlim) src = wlim;
      lds_dma16(src, (void*)&Wlds[buf][((w << 3) + (q << 2)) * 64]);
    }
  };

  if (nk > 0) {
    dma(kbeg, 0);
    __syncthreads();

    for (int t = 0; t < nk; ++t) {
      const int cur = t & 1;
      const int kt = kbeg + (t << 6);
      if (t + 1 < nk) dma(kt + 64, cur ^ 1);
      const short* arow = &A[(size_t)(mrow + l15) * ldab + kt + (lg << 3)];
      bf16x8 af0 = *(const bf16x8*)arow;
      bf16x8 af1 = *(const bf16x8*)(arow + 32);
#pragma unroll
      for (int nj = 0; nj < 4; ++nj) {
        int r = (nj << 4) + l15;
        const float* rb = &Wlds[cur][r * 64];
        int rx = r & 15;
        f32x4 u0 = *(const f32x4*)(rb + ((((lg << 1)    ) ^ rx) << 2));
        f32x4 u1 = *(const f32x4*)(rb + ((((lg << 1) | 1) ^ rx) << 2));
        f32x4 v0 = *(const f32x4*)(rb + ((((lg << 1) + 8) ^ rx) << 2));
        f32x4 v1 = *(const f32x4*)(rb + ((((lg << 1) + 9) ^ rx) << 2));
        bf16x8 b0, b1;
        uint32_t* p0 = (uint32_t*)&b0;
        uint32_t* p1 = (uint32_t*)&b1;
        p0[0] = pack2(u0[0], u0[1]); p0[1] = pack2(u0[2], u0[3]);
        p0[2] = pack2(u1[0], u1[1]); p0[3] = pack2(u1[2], u1[3]);
        p1[0] = pack2(v0[0], v0[1]); p1[1] = pack2(v0[2], v0[3]);
        p1[2] = pack2(v1[0], v1[1]); p1[3] = pack2(v1[2], v1[3]);
        acc[nj] = __builtin_amdgcn_mfma_f32_16x16x32_bf16(af0, b0, acc[nj], 0, 0, 0);
        acc[nj] = __builtin_amdgcn_mfma_f32_16x16x32_bf16(af1, b1, acc[nj], 0, 0, 0);
      }
      __syncthreads();
    }
  }

  // ---- epilogue: bf16 partials to slab ----
  short* Pb = P + (size_t)ks * 256 * Np;
#pragma unroll
  for (int nj = 0; nj < 4; ++nj) {
    int gn = n0 + (nj << 4) + l15;
#pragma unroll
    for (int r = 0; r < 4; ++r) {
      int gm = mrow + (lg << 2) + r;
      Pb[(size_t)gm * Np + gn] = f2bf(acc[nj][r]);
    }
  }
}

// ---------------- generic slab reduce (+bias+relu, zero pads) ----------------
__global__ void reduce_kernel(const short* __restrict__ P, int Np, int nchunks,
                              const float* __restrict__ bias1,
                              const float* __restrict__ bias2,
                              void* __restrict__ out, int ldc, int N,
                              int relu, int mode_f32) {
  int npack = Np >> 3;
  int idx = blockIdx.x * 256 + threadIdx.x;
  if (idx >= 256 * npack) return;
  int m = idx / npack;
  int n8 = (idx - m * npack) << 3;
  float s[8] = {0.f, 0.f, 0.f, 0.f, 0.f, 0.f, 0.f, 0.f};
  for (int ks = 0; ks < nchunks; ++ks) {
    bf16x8 v = *(const bf16x8*)&P[(size_t)ks * 256 * Np + (size_t)m * Np + n8];
#pragma unroll
    for (int j = 0; j < 8; ++j) s[j] += bf2f(v[j]);
  }
#pragma unroll
  for (int j = 0; j < 8; ++j) {
    int n = n8 + j;
    float r = 0.f;
    if (n < N) {
      r = s[j];
      if (bias1) r += bias1[n];
      if (bias2) r += bias2[n];
      if (relu) r = fmaxf(r, 0.f);
    }
    s[j] = r;
  }
  if (mode_f32) {
    float* o = (float*)out + (size_t)m * ldc + n8;
#pragma unroll
    for (int j = 0; j < 8; ++j) o[j] = s[j];
  } else {
    bf16x8 r;
#pragma unroll
    for (int j = 0; j < 8; ++j) r[j] = f2bf(s[j]);
    *(bf16x8*)((short*)out + (size_t)m * ldc + n8) = r;
  }
}

// ---------------- fused gates-reduce + LSTM -> zext bf16 ----------------
__global__ void reduce_lstm_kernel(const short* __restrict__ P, int nchunks,
                                   const float* __restrict__ b_ih,
                                   const float* __restrict__ b_hh,
                                   short* __restrict__ zext) {
  int idx = blockIdx.x * 256 + threadIdx.x;
  if (idx >= 256 * 64) return;
  int m = idx >> 6;
  int n8 = (idx & 63) << 3;
  float gi[8] = {}, gg[8] = {}, go[8] = {};
  for (int ks = 0; ks < nchunks; ++ks) {
    const short* base = P + ((size_t)ks * 256 + m) * 2048;
    bf16x8 vi = *(const bf16x8*)(base + n8);
    bf16x8 vg = *(const bf16x8*)(base + 1024 + n8);
    bf16x8 vo = *(const bf16x8*)(base + 1536 + n8);
#pragma unroll
    for (int j = 0; j < 8; ++j) {
      gi[j] += bf2f(vi[j]); gg[j] += bf2f(vg[j]); go[j] += bf2f(vo[j]);
    }
  }
  bf16x8 hv;
#pragma unroll
  for (int j = 0; j < 8; ++j) {
    int n = n8 + j;
    float i_ = gi[j] + b_ih[n] + b_hh[n];
    float g_ = gg[j] + b_ih[1024 + n] + b_hh[1024 + n];
    float o_ = go[j] + b_ih[1536 + n] + b_hh[1536 + n];
    float si = 1.f / (1.f + expf(-i_));
    float so = 1.f / (1.f + expf(-o_));
    float c = si * tanhf(g_);
    hv[j] = f2bf(so * tanhf(c));
  }
  *(bf16x8*)&zext[(size_t)m * LD_ZEXT + n8] = hv;
}

// ---- fused hm-reduce + logits GEMM + softmax + gumbel sample (4 blocks) ----
// Phm: slab [hmch][256][256] of bf16 partials for hm = z @ Wd1k^T (pre-bias).
// Each thread reduces its own A-fragments in-register (+bd1 bias, relu, bf16
// round) -- numerically identical to the old reduce->hm->load path.
__global__ __launch_bounds__(256) void logits_sample_kernel(
    const short* __restrict__ Phm, int hmch,
    const float* __restrict__ bd1k,    // [256]
    const float* __restrict__ Wd2k,    // [64][256] f32
    const float* __restrict__ bd2k,    // [64]
    const float* __restrict__ gumk,    // [256][64] f32
    const float* __restrict__ embk,    // [64][16] f32
    short* __restrict__ zext,          // [256][LD_ZEXT] bf16
    int* __restrict__ act_out, float* __restrict__ logp_out,
    float* __restrict__ ent_out, int write_emb) {
  __shared__ short Wl[64 * 264];
  const int tid = threadIdx.x;
  const int w = tid >> 6, l = tid & 63, l15 = l & 15, lg = l >> 4;
  const int mbase = blockIdx.x * 64 + w * 16;
  const int row = mbase + l15;

  // stage Wd2k -> LDS bf16
  {
    int r = tid >> 2;
    int c0 = (tid & 3) << 6;
    const float* src = Wd2k + r * 256 + c0;
    short* dst = &Wl[r * 264 + c0];
#pragma unroll
    for (int i = 0; i < 8; ++i) {
      float4 u = ((const float4*)src)[2 * i];
      float4 v = ((const float4*)src)[2 * i + 1];
      bf16x8 t;
      t[0]=f2bf(u.x); t[1]=f2bf(u.y); t[2]=f2bf(u.z); t[3]=f2bf(u.w);
      t[4]=f2bf(v.x); t[5]=f2bf(v.y); t[6]=f2bf(v.z); t[7]=f2bf(v.w);
      *(bf16x8*)(dst + 8 * i) = t;
    }
  }

  // in-register hm reduce: 8 fragments (4 kt x 2 halves), cols c0..c0+8
  bf16x8 afr[4][2];
#pragma unroll
  for (int kt = 0; kt < 4; ++kt) {
#pragma unroll
    for (int hf = 0; hf < 2; ++hf) {
      int c0 = (kt << 6) + (hf << 5) + (lg << 3);
      float s[8];
#pragma unroll
      for (int j = 0; j < 8; ++j) s[j] = bd1k[c0 + j];
      for (int ks = 0; ks < hmch; ++ks) {
        bf16x8 v = *(const bf16x8*)&Phm[((size_t)ks * 256 + row) * 256 + c0];
#pragma unroll
        for (int j = 0; j < 8; ++j) s[j] += bf2f(v[j]);
      }
#pragma unroll
      for (int j = 0; j < 8; ++j) afr[kt][hf][j] = f2bf(fmaxf(s[j], 0.f));
    }
  }
  __syncthreads();

  f32x4 acc[4];
#pragma unroll
  for (int j = 0; j < 4; ++j) acc[j] = (f32x4){0.f, 0.f, 0.f, 0.f};

#pragma unroll
  for (int kt = 0; kt < 4; ++kt) {
    int k0 = kt << 6;
#pragma unroll
    for (int nj = 0; nj < 4; ++nj) {
      const short* bp = &Wl[((nj << 4) + l15) * 264 + k0 + (lg << 3)];
      bf16x8 b0 = *(const bf16x8*)bp;
      bf16x8 b1 = *(const bf16x8*)(bp + 32);
      acc[nj] = __builtin_amdgcn_mfma_f32_16x16x32_bf16(afr[kt][0], b0, acc[nj], 0, 0, 0);
      acc[nj] = __builtin_amdgcn_mfma_f32_16x16x32_bf16(afr[kt][1], b1, acc[nj], 0, 0, 0);
    }
  }

  float bcol[4];
#pragma unroll
  for (int nj = 0; nj < 4; ++nj) bcol[nj] = bd2k[(nj << 4) + l15];

#pragma unroll
  for (int r = 0; r < 4; ++r) {
    int orow = mbase + (lg << 2) + r;
    float lv[4];
#pragma unroll
    for (int nj = 0; nj < 4; ++nj) lv[nj] = acc[nj][r] + bcol[nj];
    float mx = fmaxf(fmaxf(lv[0], lv[1]), fmaxf(lv[2], lv[3]));
#pragma unroll
    for (int off = 8; off; off >>= 1) mx = fmaxf(mx, __shfl_xor(mx, off));
    float es = expf(lv[0]-mx) + expf(lv[1]-mx) + expf(lv[2]-mx) + expf(lv[3]-mx);
#pragma unroll
    for (int off = 8; off; off >>= 1) es += __shfl_xor(es, off);
    float lse = logf(es);
    float lp[4], ent = 0.f;
#pragma unroll
    for (int nj = 0; nj < 4; ++nj) {
      lp[nj] = lv[nj] - mx - lse;
      ent += -expf(lp[nj]) * lp[nj];
    }
#pragma unroll
    for (int off = 8; off; off >>= 1) ent += __shfl_xor(ent, off);
    float bv = -3.4e38f; int bc = 64; float blp = 0.f;
#pragma unroll
    for (int nj = 0; nj < 4; ++nj) {
      int col = (nj << 4) + l15;
      float pert = lv[nj] + gumk[orow * 64 + col];
      if (pert > bv || (pert == bv && col < bc)) { bv = pert; bc = col; blp = lp[nj]; }
    }
#pragma unroll
    for (int off = 8; off; off >>= 1) {
      float ov = __shfl_xor(bv, off);
      int oc = __shfl_xor(bc, off);
      float olp = __shfl_xor(blp, off);
      if (ov > bv || (ov == bv && oc < bc)) { bv = ov; bc = oc; blp = olp; }
    }
    if (l15 == 0) {
      act_out[orow] = bc;
      logp_out[orow] = blp;
      ent_out[orow] = ent;
    }
    if (write_emb) {
      short* zr = zext + (size_t)orow * LD_ZEXT;
      zr[512 + l15] = f2bf(embk[bc * 16 + l15]);
      zr[528 + l15] = 0;
      zr[544 + l15] = 0;
      zr[560 + l15] = 0;
    }
  }
}

// ---------------- finalize (f32): action[1024] | entropy[1] | logp[256] ----------------
__global__ void finalize_kernel(const int* __restrict__ act,
                                const float* __restrict__ logp_k,
                                const float* __restrict__ ent,
                                float* __restrict__ out) {
  __shared__ float sred[4];
  int t = threadIdx.x;  // 0..255
#pragma unroll
  for (int k = 0; k < 4; ++k)
    out[t * 4 + k] = (float)act[k * 256 + t];
  float lp = 0.f;
#pragma unroll
  for (int k = 0; k < 4; ++k) lp += logp_k[k * 256 + t];
  out[1025 + t] = lp;

  float v = 0.f;
#pragma unroll
  for (int k = 0; k < 4; ++k) v += ent[k * 256 + t];
#pragma unroll
  for (int off = 32; off; off >>= 1) v += __shfl_xor(v, off);
  if ((t & 63) == 0) sred[t >> 6] = v;
  __syncthreads();
  if (t == 0) out[1024] = sred[0] + sred[1] + sred[2] + sred[3];
}

// ---------------- host launch ----------------
extern "C" void kernel_launch(void* const* d_in, const int* in_sizes, int n_in,
                              void* d_out, int out_size, void* d_ws, size_t ws_size,
                              hipStream_t stream) {
  float* out = (float*)d_out;
  char* out_bytes = (char*)d_out;
  auto sentinel = [&](int code) { hipMemsetAsync(out_bytes + 4096, code, 4, stream); };

  if (n_in < 25 || in_sizes[0] != B_SZ * 3 * 32 * 32 ||
      in_sizes[4] != FV_N * CIN_N || in_sizes[23] != LSTM_N * 528 ||
      in_sizes[9] <= 0 || in_sizes[9] > 8192 ||
      in_sizes[11] <= 0 || in_sizes[11] > 8192) {
    sentinel(0x42);
    return;
  }

  const float* actual = (const float*)d_in[0];
  const float* object = (const float*)d_in[1];
  const int* lastpos  = (const int*)d_in[2];
  const int* ep       = (const int*)d_in[3];
  const float* Wfe    = (const float*)d_in[4];
  const float* bfe    = (const float*)d_in[5];
  const float* emb_end= (const float*)d_in[6];
  const float* emb_ep = (const float*)d_in[7];
  const float* W1     = (const float*)d_in[8];
  const float* b1     = (const float*)d_in[9];
  const float* W2     = (const float*)d_in[10];
  const float* b2     = (const float*)d_in[11];
  const float* W3     = (const float*)d_in[12];
  const float* b3     = (const float*)d_in[13];
  const float* W_ih   = (const float*)d_in[14];
  const float* b_ih   = (const float*)d_in[16];
  const float* b_hh   = (const float*)d_in[17];
  const float* Wd1    = (const float*)d_in[18];
  const float* bd1    = (const float*)d_in[19];
  const float* Wd2    = (const float*)d_in[20];
  const float* bd2    = (const float*)d_in[21];
  const float* embdec = (const float*)d_in[22];
  const float* Wout   = (const float*)d_in[23];
  const float* bout   = (const float*)d_in[24];

  const int H1 = in_sizes[9];
  const int H2 = in_sizes[11];
  const int ldh1 = 64 * ((H1 + 63) / 64);
  const int ldh2 = 64 * ((H2 + 63) / 64);

  // ---- workspace ----
  char* wsb = (char*)d_ws;
  size_t off = 0;
  auto alloc = [&](size_t bytes) {
    char* p = wsb + off;
    off += (bytes + 255) & ~(size_t)255;
    return p;
  };
  float* logpk = (float*)alloc(1024 * 4);
  float* entk  = (float*)alloc(1024 * 4);
  int*   actk  = (int*)alloc(1024 * 4);
  float* gumb  = (float*)alloc(4 * 16384 * 4);
  short* xb    = (short*)alloc((size_t)B_SZ * CIN_N * 2);
  short* feats = (short*)alloc((size_t)B_SZ * LD_FEAT * 2);
  short* h1    = (short*)alloc((size_t)B_SZ * ldh1 * 2);
  short* h2    = (short*)alloc((size_t)B_SZ * ldh2 * 2);
  short* h3    = (short*)alloc((size_t)B_SZ * 512 * 2);
  short* zextA = (short*)alloc((size_t)B_SZ * LD_ZEXT * 2);
  short* zextB = (short*)alloc((size_t)B_SZ * LD_ZEXT * 2);
  if (off + (8 << 20) > ws_size) {
    sentinel(0x43);
    return;
  }
  short* slab = (short*)(wsb + off);
  const size_t slab_bytes = ws_size - off;

  // fuse: 0 = plain reduce, 1 = reduce+LSTM, 2 = no reduce (caller fuses)
  // returns chunk count used.
  auto gemm = [&](const short* A, int ldab, const float* Wm, int ldw, int Kiter,
                  const float* bb1, const float* bb2,
                  void* C, int ldc, int N, int relu, int fuse) -> int {
    int nblk = (N + 63) / 64;
    int Np = nblk * 64;
    int tiles = Kiter >> 6;
    int c = (384 + nblk - 1) / nblk;
    if (c > tiles) c = tiles;
    size_t cap = slab_bytes / ((size_t)256 * Np * 2);
    if ((size_t)c > cap) c = (int)cap;
    if (c < 1) c = 1;
    int ct = (tiles + c - 1) / c;
    int kc = 64 * ct;
    int chunks = (tiles + ct - 1) / ct;
    dim3 g(2 * nblk, chunks);
    gemm6_kernel<<<g, dim3(512), 0, stream>>>(
        A, ldab, Wm, ldw, Wm + (size_t)N * ldw, slab, nblk, N, Kiter, kc, chunks);
    if (fuse == 1) {
      reduce_lstm_kernel<<<dim3(64), dim3(256), 0, stream>>>(
          slab, chunks, bb1, bb2, (short*)C);
    } else if (fuse == 0) {
      int npack = Np >> 3;
      reduce_kernel<<<dim3((256 * npack + 255) / 256), dim3(256), 0, stream>>>(
          slab, Np, chunks, bb1, bb2, C, ldc, N, relu, 0);
    }
    return chunks;
  };

  // 0. concat+cvt canvases; gumbel table
  concat_cvt_kernel<<<dim3(768), dim3(256), 0, stream>>>(actual, object, xb);
  gumbel_kernel<<<dim3(256), dim3(256), 0, stream>>>(gumb);
  // 1. feats = relu(xb @ Wfe^T + bfe)
  gemm(xb, CIN_N, Wfe, CIN_N, CIN_N, bfe, nullptr, feats, LD_FEAT, FV_N, 1, 0);
  // 2. embeddings + pad
  fill_embs_kernel<<<dim3(B_SZ), dim3(64), 0, stream>>>(lastpos, ep, emb_end, emb_ep, feats);
  // 3..5. MLP (Kiter = A's padded width; A pad is zero so W overread is harmless)
  gemm(feats, LD_FEAT, W1, FEAT_N, LD_FEAT, b1, nullptr, h1, ldh1, H1, 1, 0);
  gemm(h1, ldh1, W2, H1, ldh1, b2, nullptr, h2, ldh2, H2, 1, 0);
  gemm(h2, ldh2, W3, H2, ldh2, b3, nullptr, h3, 512, LSTM_N, 1, 0);
  // 6. gates GEMM + fused reduce/LSTM -> zextA
  gemm(h3, 512, W_ih, LSTM_N, 512, b_ih, b_hh, zextA, LD_ZEXT, 4 * LSTM_N, 0, 1);

  // 7. autoregressive decoder (hm reduce fused into sampler)
  short* zcur = zextA;
  short* znxt = zextB;
  for (int k = 0; k < 4; ++k) {
    const float* Wd1k = Wd1 + (size_t)k * 256 * LSTM_N;
    const float* bd1k = bd1 + (size_t)k * 256;
    const float* Wd2k = Wd2 + (size_t)k * ACT_N * 256;
    const float* bd2k = bd2 + (size_t)k * ACT_N;
    const float* embk = embdec + (size_t)k * ACT_N * 16;
    // hm partials -> slab only (fuse=2)
    int hmch = gemm(zcur, LD_ZEXT, Wd1k, LSTM_N, 512, nullptr, nullptr,
                    nullptr, 0, 256, 1, 2);
    logits_sample_kernel<<<dim3(4), dim3(256), 0, stream>>>(
        slab, hmch, bd1k, Wd2k, bd2k, gumb + k * 16384, embk, zcur,
        actk + k * B_SZ, logpk + k * B_SZ, entk + k * B_SZ, (k < 3) ? 1 : 0);
    if (k < 3) {
      gemm(zcur, LD_ZEXT, Wout, 528, LD_ZEXT, bout, nullptr, znxt, LD_ZEXT, LSTM_N, 1, 0);
      short* t = zcur; zcur = znxt; znxt = t;
    }
  }

  // 8. outputs
  finalize_kernel<<<dim3(1), dim3(256), 0, stream>>>(actk, logpk, entk, out);
}

// Round 21
// 262.978 us; speedup vs baseline: 1.1515x; 1.1515x over previous
//
#include <hip/hip_runtime.h>
#include <hip/hip_bf16.h>
#include <stdint.h>

// ---------------- constants ----------------
#define B_SZ   256
#define LSTM_N 512
#define FEAT_N 4632
#define FV_N   4608
#define CIN_N  6144
#define HALF_CIN 3072
#define ACT_N  64
#define LD_FEAT 4672   // 64-mult >= 4632
#define LD_ZEXT 576    // 64-mult >= 528

typedef __attribute__((ext_vector_type(8))) short bf16x8;
typedef __attribute__((ext_vector_type(4))) float f32x4;

__device__ __forceinline__ short f2bf(float f) {
  uint32_t u = __float_as_uint(f);
  u += 0x7FFFu + ((u >> 16) & 1u);
  return (short)(u >> 16);
}
__device__ __forceinline__ float bf2f(short s) {
  return __uint_as_float(((uint32_t)(uint16_t)s) << 16);
}
// truncation pack: two f32 -> two bf16 in one u32
__device__ __forceinline__ uint32_t pack2(float x, float y) {
  return (__float_as_uint(x) >> 16) | (__float_as_uint(y) & 0xffff0000u);
}

// async global->LDS DMA, 16B per lane; LDS dest = wave-uniform base + lane*16
typedef __attribute__((address_space(3))) void lds_void_t;
typedef const __attribute__((address_space(1))) void gbl_void_t;
__device__ __forceinline__ void lds_dma16(const void* g, void* l) {
  __builtin_amdgcn_global_load_lds((gbl_void_t*)g, (lds_void_t*)l, 16, 0, 0);
}

// ---------------- threefry2x32 (matches jax) ----------------
__device__ __forceinline__ uint32_t rotl32(uint32_t x, int r) {
  return (x << r) | (x >> (32 - r));
}
__device__ __forceinline__ void threefry2x32(uint32_t k0, uint32_t k1,
                                             uint32_t x0, uint32_t x1,
                                             uint32_t& o0, uint32_t& o1) {
  uint32_t k2 = k0 ^ k1 ^ 0x1BD11BDAu;
  x0 += k0; x1 += k1;
  x0 += x1; x1 = rotl32(x1, 13); x1 ^= x0;
  x0 += x1; x1 = rotl32(x1, 15); x1 ^= x0;
  x0 += x1; x1 = rotl32(x1, 26); x1 ^= x0;
  x0 += x1; x1 = rotl32(x1,  6); x1 ^= x0;
  x0 += k1; x1 += k2 + 1u;
  x0 += x1; x1 = rotl32(x1, 17); x1 ^= x0;
  x0 += x1; x1 = rotl32(x1, 29); x1 ^= x0;
  x0 += x1; x1 = rotl32(x1, 16); x1 ^= x0;
  x0 += x1; x1 = rotl32(x1, 24); x1 ^= x0;
  x0 += k2; x1 += k0 + 2u;
  x0 += x1; x1 = rotl32(x1, 13); x1 ^= x0;
  x0 += x1; x1 = rotl32(x1, 15); x1 ^= x0;
  x0 += x1; x1 = rotl32(x1, 26); x1 ^= x0;
  x0 += x1; x1 = rotl32(x1,  6); x1 ^= x0;
  x0 += k0; x1 += k1 + 3u;
  x0 += x1; x1 = rotl32(x1, 17); x1 ^= x0;
  x0 += x1; x1 = rotl32(x1, 29); x1 ^= x0;
  x0 += x1; x1 = rotl32(x1, 16); x1 ^= x0;
  x0 += x1; x1 = rotl32(x1, 24); x1 ^= x0;
  x0 += k1; x1 += k2 + 4u;
  x0 += x1; x1 = rotl32(x1, 13); x1 ^= x0;
  x0 += x1; x1 = rotl32(x1, 15); x1 ^= x0;
  x0 += x1; x1 = rotl32(x1, 26); x1 ^= x0;
  x0 += x1; x1 = rotl32(x1,  6); x1 ^= x0;
  x0 += k2; x1 += k0 + 5u;
  o0 = x0; o1 = x1;
}

// ---------------- concat canvases + cvt to bf16 ----------------
__global__ void concat_cvt_kernel(const float* __restrict__ act,
                                  const float* __restrict__ obj,
                                  short* __restrict__ xb) {
  int idx = blockIdx.x * 256 + threadIdx.x;
  if (idx >= B_SZ * 768) return;
  int row = idx / 768;
  int c8 = (idx - row * 768) * 8;
  const float* src = (c8 < HALF_CIN) ? (act + (size_t)row * HALF_CIN + c8)
                                     : (obj + (size_t)row * HALF_CIN + (c8 - HALF_CIN));
  float4 u = ((const float4*)src)[0];
  float4 v = ((const float4*)src)[1];
  bf16x8 r;
  r[0]=f2bf(u.x); r[1]=f2bf(u.y); r[2]=f2bf(u.z); r[3]=f2bf(u.w);
  r[4]=f2bf(v.x); r[5]=f2bf(v.y); r[6]=f2bf(v.z); r[7]=f2bf(v.w);
  *(bf16x8*)&xb[(size_t)row * CIN_N + c8] = r;
}

// ---------------- gumbel table: gum[4][256][64] ----------------
__global__ void gumbel_kernel(float* __restrict__ gum) {
  int idx = blockIdx.x * 256 + threadIdx.x;
  if (idx >= 4 * 16384) return;
  int k = idx >> 14;
  uint32_t j = (uint32_t)(idx & 16383);
  uint32_t f0, f1, o0, o1, bits;
  threefry2x32(0u, 42u, 0u, (uint32_t)k, f0, f1);
  if (j < 8192u) { threefry2x32(f0, f1, j, j + 8192u, o0, o1); bits = o0; }
  else           { threefry2x32(f0, f1, j - 8192u, j, o0, o1); bits = o1; }
  const float tiny = 1.17549435e-38f;
  float fu = __uint_as_float((bits >> 9) | 0x3f800000u) - 1.0f;
  float u = fmaxf(tiny, fu * (1.0f - tiny) + tiny);
  gum[idx] = -logf(-logf(u));
}

// ---------------- embeddings into feats + zero pad ----------------
__global__ void fill_embs_kernel(const int* __restrict__ lastpos,
                                 const int* __restrict__ ep,
                                 const float* __restrict__ emb_end,
                                 const float* __restrict__ emb_ep,
                                 short* __restrict__ feats) {
  int b = blockIdx.x;
  int t = threadIdx.x;   // 0..63
  short* row = feats + (size_t)b * LD_FEAT;
  if (t < 16)      row[FV_N + t] = f2bf(emb_end[lastpos[b] * 16 + t]);
  else if (t < 24) row[FV_N + 16 + (t - 16)] = f2bf(emb_ep[ep[b] * 8 + (t - 16)]);
  else             row[FV_N + t] = 0;
}

// ---------------- GEMM v11: global_load_lds W staging, 128m x 64n per block ----------
// A bf16 [256][ldab] (zero-padded), W f32 rows len ldw; slab-only output.
// W tile (64n x 64k f32, 16KB) DMA'd into LDS, 16B-granule XOR swizzle (j ^ (r&15))
// applied on the SOURCE address (LDS written linearly by HW).
__global__ __launch_bounds__(512, 6) void gemm6_kernel(
    const short* __restrict__ A, int ldab,
    const float* __restrict__ W, int ldw,
    const float* __restrict__ Wend,           // W + N*ldw
    short* __restrict__ P, int nblk,
    int N, int Kiter, int kc, int nchunks) {
  __shared__ float Wlds[2][64 * 64];

  const int tid = threadIdx.x;
  const int w = tid >> 6, l = tid & 63, l15 = l & 15, lg = l >> 4;
  const int mb = blockIdx.x & 1;
  const int n0 = (blockIdx.x >> 1) * 64;
  const int Np = nblk * 64;
  const int ks = blockIdx.y;
  const int kbeg = ks * kc;
  const int kend = (kbeg + kc < Kiter) ? (kbeg + kc) : Kiter;
  const int nk = (kend - kbeg) >> 6;
  const int mrow = mb * 128 + (w << 4);      // 16 m-rows per wave

  const char* wlim = (const char*)Wend - 16;

  f32x4 acc[4];
#pragma unroll
  for (int j = 0; j < 4; ++j) acc[j] = (f32x4){0.f, 0.f, 0.f, 0.f};

  // DMA one 64x64-f32 W tile at k-offset kt into buf. 16 instrs (2 per wave).
  auto dma = [&](int kt, int buf) {
#pragma unroll
    for (int q = 0; q < 2; ++q) {
      int r = (w << 3) + (q << 2) + (l >> 4);   // tile row 0..63
      int gn = n0 + r; if (gn >= N) gn = N - 1;
      int g16 = (l & 15) ^ (r & 15);            // source granule (pre-swizzle)
      const char* src = (const char*)(W + (size_t)gn * ldw + kt) + g16 * 16;
      if (src > wlim) src = wlim;
      lds_dma16(src, (void*)&Wlds[buf][((w << 3) + (q << 2)) * 64]);
    }
  };

  if (nk > 0) {
    dma(kbeg, 0);
    __syncthreads();

    for (int t = 0; t < nk; ++t) {
      const int cur = t & 1;
      const int kt = kbeg + (t << 6);
      if (t + 1 < nk) dma(kt + 64, cur ^ 1);
      // A fragments (bf16, L2-resident)
      const short* arow = &A[(size_t)(mrow + l15) * ldab + kt + (lg << 3)];
      bf16x8 af0 = *(const bf16x8*)arow;
      bf16x8 af1 = *(const bf16x8*)(arow + 32);
      // W fragments from LDS (swizzled granules) + MFMA
#pragma unroll
      for (int nj = 0; nj < 4; ++nj) {
        int r = (nj << 4) + l15;
        const float* rb = &Wlds[cur][r * 64];
        int rx = r & 15;
        f32x4 u0 = *(const f32x4*)(rb + ((((lg << 1)    ) ^ rx) << 2));
        f32x4 u1 = *(const f32x4*)(rb + ((((lg << 1) | 1) ^ rx) << 2));
        f32x4 v0 = *(const f32x4*)(rb + ((((lg << 1) + 8) ^ rx) << 2));
        f32x4 v1 = *(const f32x4*)(rb + ((((lg << 1) + 9) ^ rx) << 2));
        bf16x8 b0, b1;
        uint32_t* p0 = (uint32_t*)&b0;
        uint32_t* p1 = (uint32_t*)&b1;
        p0[0] = pack2(u0[0], u0[1]); p0[1] = pack2(u0[2], u0[3]);
        p0[2] = pack2(u1[0], u1[1]); p0[3] = pack2(u1[2], u1[3]);
        p1[0] = pack2(v0[0], v0[1]); p1[1] = pack2(v0[2], v0[3]);
        p1[2] = pack2(v1[0], v1[1]); p1[3] = pack2(v1[2], v1[3]);
        acc[nj] = __builtin_amdgcn_mfma_f32_16x16x32_bf16(af0, b0, acc[nj], 0, 0, 0);
        acc[nj] = __builtin_amdgcn_mfma_f32_16x16x32_bf16(af1, b1, acc[nj], 0, 0, 0);
      }
      __syncthreads();
    }
  }

  // ---- epilogue: bf16 partials to slab ----
  short* Pb = P + (size_t)ks * 256 * Np;
#pragma unroll
  for (int nj = 0; nj < 4; ++nj) {
    int gn = n0 + (nj << 4) + l15;
#pragma unroll
    for (int r = 0; r < 4; ++r) {
      int gm = mrow + (lg << 2) + r;
      Pb[(size_t)gm * Np + gn] = f2bf(acc[nj][r]);
    }
  }
}

// ---------------- generic slab reduce (+bias+relu, zero pads) ----------------
__global__ void reduce_kernel(const short* __restrict__ P, int Np, int nchunks,
                              const float* __restrict__ bias1,
                              const float* __restrict__ bias2,
                              void* __restrict__ out, int ldc, int N,
                              int relu, int mode_f32) {
  int npack = Np >> 3;
  int idx = blockIdx.x * 256 + threadIdx.x;
  if (idx >= 256 * npack) return;
  int m = idx / npack;
  int n8 = (idx - m * npack) << 3;
  float s[8] = {0.f, 0.f, 0.f, 0.f, 0.f, 0.f, 0.f, 0.f};
  for (int ks = 0; ks < nchunks; ++ks) {
    bf16x8 v = *(const bf16x8*)&P[(size_t)ks * 256 * Np + (size_t)m * Np + n8];
#pragma unroll
    for (int j = 0; j < 8; ++j) s[j] += bf2f(v[j]);
  }
#pragma unroll
  for (int j = 0; j < 8; ++j) {
    int n = n8 + j;
    float r = 0.f;
    if (n < N) {
      r = s[j];
      if (bias1) r += bias1[n];
      if (bias2) r += bias2[n];
      if (relu) r = fmaxf(r, 0.f);
    }
    s[j] = r;
  }
  if (mode_f32) {
    float* o = (float*)out + (size_t)m * ldc + n8;
#pragma unroll
    for (int j = 0; j < 8; ++j) o[j] = s[j];
  } else {
    bf16x8 r;
#pragma unroll
    for (int j = 0; j < 8; ++j) r[j] = f2bf(s[j]);
    *(bf16x8*)((short*)out + (size_t)m * ldc + n8) = r;
  }
}

// ---------------- fused gates-reduce + LSTM -> zext bf16 ----------------
__global__ void reduce_lstm_kernel(const short* __restrict__ P, int nchunks,
                                   const float* __restrict__ b_ih,
                                   const float* __restrict__ b_hh,
                                   short* __restrict__ zext) {
  int idx = blockIdx.x * 256 + threadIdx.x;
  if (idx >= 256 * 64) return;
  int m = idx >> 6;
  int n8 = (idx & 63) << 3;
  float gi[8] = {}, gg[8] = {}, go[8] = {};
  for (int ks = 0; ks < nchunks; ++ks) {
    const short* base = P + ((size_t)ks * 256 + m) * 2048;
    bf16x8 vi = *(const bf16x8*)(base + n8);
    bf16x8 vg = *(const bf16x8*)(base + 1024 + n8);
    bf16x8 vo = *(const bf16x8*)(base + 1536 + n8);
#pragma unroll
    for (int j = 0; j < 8; ++j) {
      gi[j] += bf2f(vi[j]); gg[j] += bf2f(vg[j]); go[j] += bf2f(vo[j]);
    }
  }
  bf16x8 hv;
#pragma unroll
  for (int j = 0; j < 8; ++j) {
    int n = n8 + j;
    float i_ = gi[j] + b_ih[n] + b_hh[n];
    float g_ = gg[j] + b_ih[1024 + n] + b_hh[1024 + n];
    float o_ = go[j] + b_ih[1536 + n] + b_hh[1536 + n];
    float si = 1.f / (1.f + expf(-i_));
    float so = 1.f / (1.f + expf(-o_));
    float c = si * tanhf(g_);
    hv[j] = f2bf(so * tanhf(c));
  }
  *(bf16x8*)&zext[(size_t)m * LD_ZEXT + n8] = hv;
}

// ---------------- fused logits GEMM + softmax + gumbel sample (4 blocks) ----------------
__global__ __launch_bounds__(256) void logits_sample_kernel(
    const short* __restrict__ hm,      // [256][256] bf16
    const float* __restrict__ Wd2k,    // [64][256] f32
    const float* __restrict__ bd2k,    // [64]
    const float* __restrict__ gumk,    // [256][64] f32
    const float* __restrict__ embk,    // [64][16] f32
    short* __restrict__ zext,          // [256][LD_ZEXT] bf16
    int* __restrict__ act_out, float* __restrict__ logp_out,
    float* __restrict__ ent_out, int write_emb) {
  __shared__ short Wl[64 * 264];
  const int tid = threadIdx.x;
  const int w = tid >> 6, l = tid & 63, l15 = l & 15, lg = l >> 4;
  const int mbase = blockIdx.x * 64 + w * 16;

  {
    int r = tid >> 2;
    int c0 = (tid & 3) << 6;
    const float* src = Wd2k + r * 256 + c0;
    short* dst = &Wl[r * 264 + c0];
#pragma unroll
    for (int i = 0; i < 8; ++i) {
      float4 u = ((const float4*)src)[2 * i];
      float4 v = ((const float4*)src)[2 * i + 1];
      bf16x8 t;
      t[0]=f2bf(u.x); t[1]=f2bf(u.y); t[2]=f2bf(u.z); t[3]=f2bf(u.w);
      t[4]=f2bf(v.x); t[5]=f2bf(v.y); t[6]=f2bf(v.z); t[7]=f2bf(v.w);
      *(bf16x8*)(dst + 8 * i) = t;
    }
  }
  __syncthreads();

  f32x4 acc[4];
#pragma unroll
  for (int j = 0; j < 4; ++j) acc[j] = (f32x4){0.f, 0.f, 0.f, 0.f};

#pragma unroll
  for (int kt = 0; kt < 4; ++kt) {
    int k0 = kt << 6;
    const short* arow = &hm[(size_t)(mbase + l15) * 256 + k0 + (lg << 3)];
    bf16x8 af0 = *(const bf16x8*)arow;
    bf16x8 af1 = *(const bf16x8*)(arow + 32);
#pragma unroll
    for (int nj = 0; nj < 4; ++nj) {
      const short* bp = &Wl[((nj << 4) + l15) * 264 + k0 + (lg << 3)];
      bf16x8 b0 = *(const bf16x8*)bp;
      bf16x8 b1 = *(const bf16x8*)(bp + 32);
      acc[nj] = __builtin_amdgcn_mfma_f32_16x16x32_bf16(af0, b0, acc[nj], 0, 0, 0);
      acc[nj] = __builtin_amdgcn_mfma_f32_16x16x32_bf16(af1, b1, acc[nj], 0, 0, 0);
    }
  }

  float bcol[4];
#pragma unroll
  for (int nj = 0; nj < 4; ++nj) bcol[nj] = bd2k[(nj << 4) + l15];

#pragma unroll
  for (int r = 0; r < 4; ++r) {
    int row = mbase + (lg << 2) + r;
    float lv[4];
#pragma unroll
    for (int nj = 0; nj < 4; ++nj) lv[nj] = acc[nj][r] + bcol[nj];
    float mx = fmaxf(fmaxf(lv[0], lv[1]), fmaxf(lv[2], lv[3]));
#pragma unroll
    for (int off = 8; off; off >>= 1) mx = fmaxf(mx, __shfl_xor(mx, off));
    float es = expf(lv[0]-mx) + expf(lv[1]-mx) + expf(lv[2]-mx) + expf(lv[3]-mx);
#pragma unroll
    for (int off = 8; off; off >>= 1) es += __shfl_xor(es, off);
    float lse = logf(es);
    float lp[4], ent = 0.f;
#pragma unroll
    for (int nj = 0; nj < 4; ++nj) {
      lp[nj] = lv[nj] - mx - lse;
      ent += -expf(lp[nj]) * lp[nj];
    }
#pragma unroll
    for (int off = 8; off; off >>= 1) ent += __shfl_xor(ent, off);
    float bv = -3.4e38f; int bc = 64; float blp = 0.f;
#pragma unroll
    for (int nj = 0; nj < 4; ++nj) {
      int col = (nj << 4) + l15;
      float pert = lv[nj] + gumk[row * 64 + col];
      if (pert > bv || (pert == bv && col < bc)) { bv = pert; bc = col; blp = lp[nj]; }
    }
#pragma unroll
    for (int off = 8; off; off >>= 1) {
      float ov = __shfl_xor(bv, off);
      int oc = __shfl_xor(bc, off);
      float olp = __shfl_xor(blp, off);
      if (ov > bv || (ov == bv && oc < bc)) { bv = ov; bc = oc; blp = olp; }
    }
    if (l15 == 0) {
      act_out[row] = bc;
      logp_out[row] = blp;
      ent_out[row] = ent;
    }
    if (write_emb) {
      short* zr = zext + (size_t)row * LD_ZEXT;
      zr[512 + l15] = f2bf(embk[bc * 16 + l15]);
      zr[528 + l15] = 0;
      zr[544 + l15] = 0;
      zr[560 + l15] = 0;
    }
  }
}

// ---------------- finalize (f32): action[1024] | entropy[1] | logp[256] ----------------
__global__ void finalize_kernel(const int* __restrict__ act,
                                const float* __restrict__ logp_k,
                                const float* __restrict__ ent,
                                float* __restrict__ out) {
  __shared__ float sred[4];
  int t = threadIdx.x;  // 0..255
#pragma unroll
  for (int k = 0; k < 4; ++k)
    out[t * 4 + k] = (float)act[k * 256 + t];
  float lp = 0.f;
#pragma unroll
  for (int k = 0; k < 4; ++k) lp += logp_k[k * 256 + t];
  out[1025 + t] = lp;

  float v = 0.f;
#pragma unroll
  for (int k = 0; k < 4; ++k) v += ent[k * 256 + t];
#pragma unroll
  for (int off = 32; off; off >>= 1) v += __shfl_xor(v, off);
  if ((t & 63) == 0) sred[t >> 6] = v;
  __syncthreads();
  if (t == 0) out[1024] = sred[0] + sred[1] + sred[2] + sred[3];
}

// ---------------- host launch ----------------
extern "C" void kernel_launch(void* const* d_in, const int* in_sizes, int n_in,
                              void* d_out, int out_size, void* d_ws, size_t ws_size,
                              hipStream_t stream) {
  float* out = (float*)d_out;
  char* out_bytes = (char*)d_out;
  auto sentinel = [&](int code) { hipMemsetAsync(out_bytes + 4096, code, 4, stream); };

  if (n_in < 25 || in_sizes[0] != B_SZ * 3 * 32 * 32 ||
      in_sizes[4] != FV_N * CIN_N || in_sizes[23] != LSTM_N * 528 ||
      in_sizes[9] <= 0 || in_sizes[9] > 8192 ||
      in_sizes[11] <= 0 || in_sizes[11] > 8192) {
    sentinel(0x42);
    return;
  }

  const float* actual = (const float*)d_in[0];
  const float* object = (const float*)d_in[1];
  const int* lastpos  = (const int*)d_in[2];
  const int* ep       = (const int*)d_in[3];
  const float* Wfe    = (const float*)d_in[4];
  const float* bfe    = (const float*)d_in[5];
  const float* emb_end= (const float*)d_in[6];
  const float* emb_ep = (const float*)d_in[7];
  const float* W1     = (const float*)d_in[8];
  const float* b1     = (const float*)d_in[9];
  const float* W2     = (const float*)d_in[10];
  const float* b2     = (const float*)d_in[11];
  const float* W3     = (const float*)d_in[12];
  const float* b3     = (const float*)d_in[13];
  const float* W_ih   = (const float*)d_in[14];
  const float* b_ih   = (const float*)d_in[16];
  const float* b_hh   = (const float*)d_in[17];
  const float* Wd1    = (const float*)d_in[18];
  const float* bd1    = (const float*)d_in[19];
  const float* Wd2    = (const float*)d_in[20];
  const float* bd2    = (const float*)d_in[21];
  const float* embdec = (const float*)d_in[22];
  const float* Wout   = (const float*)d_in[23];
  const float* bout   = (const float*)d_in[24];

  const int H1 = in_sizes[9];
  const int H2 = in_sizes[11];
  const int ldh1 = 64 * ((H1 + 63) / 64);
  const int ldh2 = 64 * ((H2 + 63) / 64);

  // ---- workspace ----
  char* wsb = (char*)d_ws;
  size_t off = 0;
  auto alloc = [&](size_t bytes) {
    char* p = wsb + off;
    off += (bytes + 255) & ~(size_t)255;
    return p;
  };
  float* logpk = (float*)alloc(1024 * 4);
  float* entk  = (float*)alloc(1024 * 4);
  int*   actk  = (int*)alloc(1024 * 4);
  float* gumb  = (float*)alloc(4 * 16384 * 4);
  short* xb    = (short*)alloc((size_t)B_SZ * CIN_N * 2);
  short* feats = (short*)alloc((size_t)B_SZ * LD_FEAT * 2);
  short* h1    = (short*)alloc((size_t)B_SZ * ldh1 * 2);
  short* h2    = (short*)alloc((size_t)B_SZ * ldh2 * 2);
  short* h3    = (short*)alloc((size_t)B_SZ * 512 * 2);
  short* zextA = (short*)alloc((size_t)B_SZ * LD_ZEXT * 2);
  short* zextB = (short*)alloc((size_t)B_SZ * LD_ZEXT * 2);
  short* hm    = (short*)alloc((size_t)B_SZ * 256 * 2);
  if (off + (8 << 20) > ws_size) {
    sentinel(0x43);
    return;
  }
  short* slab = (short*)(wsb + off);
  const size_t slab_bytes = ws_size - off;

  // fuse: 0 = plain reduce, 1 = reduce+LSTM
  // Kiter: 64-mult iterate width (A's zero-padded stride window); ldw: true W row len
  auto gemm = [&](const short* A, int ldab, const float* Wm, int ldw, int Kiter,
                  const float* bb1, const float* bb2,
                  void* C, int ldc, int N, int relu, int fuse) {
    int nblk = (N + 63) / 64;
    int Np = nblk * 64;
    int tiles = Kiter >> 6;
    int c = (384 + nblk - 1) / nblk;
    if (c > tiles) c = tiles;
    size_t cap = slab_bytes / ((size_t)256 * Np * 2);
    if ((size_t)c > cap) c = (int)cap;
    if (c < 1) c = 1;
    int ct = (tiles + c - 1) / c;
    int kc = 64 * ct;
    int chunks = (tiles + ct - 1) / ct;
    dim3 g(2 * nblk, chunks);
    gemm6_kernel<<<g, dim3(512), 0, stream>>>(
        A, ldab, Wm, ldw, Wm + (size_t)N * ldw, slab, nblk, N, Kiter, kc, chunks);
    if (fuse == 1) {
      reduce_lstm_kernel<<<dim3(64), dim3(256), 0, stream>>>(
          slab, chunks, bb1, bb2, (short*)C);
    } else {
      int npack = Np >> 3;
      reduce_kernel<<<dim3((256 * npack + 255) / 256), dim3(256), 0, stream>>>(
          slab, Np, chunks, bb1, bb2, C, ldc, N, relu, 0);
    }
  };

  // 0. concat+cvt canvases; gumbel table
  concat_cvt_kernel<<<dim3(768), dim3(256), 0, stream>>>(actual, object, xb);
  gumbel_kernel<<<dim3(256), dim3(256), 0, stream>>>(gumb);
  // 1. feats = relu(xb @ Wfe^T + bfe)
  gemm(xb, CIN_N, Wfe, CIN_N, CIN_N, bfe, nullptr, feats, LD_FEAT, FV_N, 1, 0);
  // 2. embeddings + pad
  fill_embs_kernel<<<dim3(B_SZ), dim3(64), 0, stream>>>(lastpos, ep, emb_end, emb_ep, feats);
  // 3..5. MLP (Kiter = A's padded width; A pad is zero so W overread is harmless)
  gemm(feats, LD_FEAT, W1, FEAT_N, LD_FEAT, b1, nullptr, h1, ldh1, H1, 1, 0);
  gemm(h1, ldh1, W2, H1, ldh1, b2, nullptr, h2, ldh2, H2, 1, 0);
  gemm(h2, ldh2, W3, H2, ldh2, b3, nullptr, h3, 512, LSTM_N, 1, 0);
  // 6. gates GEMM + fused reduce/LSTM -> zextA
  gemm(h3, 512, W_ih, LSTM_N, 512, b_ih, b_hh, zextA, LD_ZEXT, 4 * LSTM_N, 0, 1);

  // 7. autoregressive decoder
  short* zcur = zextA;
  short* znxt = zextB;
  for (int k = 0; k < 4; ++k) {
    const float* Wd1k = Wd1 + (size_t)k * 256 * LSTM_N;
    const float* bd1k = bd1 + (size_t)k * 256;
    const float* Wd2k = Wd2 + (size_t)k * ACT_N * 256;
    const float* bd2k = bd2 + (size_t)k * ACT_N;
    const float* embk = embdec + (size_t)k * ACT_N * 16;
    // hm = relu(z @ Wd1k^T + bd1k)  (Kiter=512: exclude emb cols of zext)
    gemm(zcur, LD_ZEXT, Wd1k, LSTM_N, 512, bd1k, nullptr, hm, 256, 256, 1, 0);
    logits_sample_kernel<<<dim3(4), dim3(256), 0, stream>>>(
        hm, Wd2k, bd2k, gumb + k * 16384, embk, zcur,
        actk + k * B_SZ, logpk + k * B_SZ, entk + k * B_SZ, (k < 3) ? 1 : 0);
    if (k < 3) {
      // z' = relu([z, emb] @ Wout^T + bout)  (Kiter=576: cols 528..575 are zero)
      gemm(zcur, LD_ZEXT, Wout, 528, LD_ZEXT, bout, nullptr, znxt, LD_ZEXT, LSTM_N, 1, 0);
      short* t = zcur; zcur = znxt; znxt = t;
    }
  }

  // 8. outputs
  finalize_kernel<<<dim3(1), dim3(256), 0, stream>>>(actk, logpk, entk, out);
}